// Round 1
// baseline (563.200 us; speedup 1.0000x reference)
//
#include <hip/hip_runtime.h>
#include <math.h>

#define B_ 32
#define H_ 112
#define W_ 112
#define C_ 192
#define NPOS (B_*H_*W_)      // 401408
#define C4 (C_/4)            // 48

typedef float f32x4 __attribute__((ext_vector_type(4)));

// ---------------- Kernel 1: per-position channel mean + max ----------------
// 16-lane group per position (4 positions per wave, all 64 lanes active).
// Each lane loads 3 float4 (48 B) -> 16 lanes cover the 192 channels.
__global__ __launch_bounds__(256) void reduce_kernel(const float* __restrict__ x,
                                                     float2* __restrict__ ws2) {
    const int tid = threadIdx.x;
    const int i   = tid & 15;          // lane within 16-group
    const int grp = tid >> 4;          // 16 groups per block
    const int p   = blockIdx.x * 16 + grp;   // grid sized exactly: NPOS/16 blocks

    const float4* xp = (const float4*)(x + (size_t)p * C_);
    float4 a = xp[i];
    float4 b = xp[i + 16];
    float4 c = xp[i + 32];
    float s = ((a.x + a.y) + (a.z + a.w))
            + ((b.x + b.y) + (b.z + b.w))
            + ((c.x + c.y) + (c.z + c.w));
    float m = fmaxf(fmaxf(fmaxf(a.x, a.y), fmaxf(a.z, a.w)),
             fmaxf(fmaxf(fmaxf(b.x, b.y), fmaxf(b.z, b.w)),
                   fmaxf(fmaxf(c.x, c.y), fmaxf(c.z, c.w))));
    // 4-level butterfly within the 16-lane group (xor offsets stay in-group)
    #pragma unroll
    for (int off = 8; off > 0; off >>= 1) {
        s += __shfl_xor(s, off);
        m = fmaxf(m, __shfl_xor(m, off));
    }
    if (i == 0) {
        float2 r;
        r.x = s * (1.0f / (float)C_);
        r.y = m;
        ws2[p] = r;   // lanes 0/16/32/48 write 4 consecutive float2s
    }
}

// ------- Kernel 2 (fused): 7x7 conv + sigmoid + broadcast multiply ---------
// One block per 64 consecutive positions. Threads 0..63 compute att into LDS
// while all 12 x-float4 loads per thread are already in flight (issued before
// the barrier). Blocks traverse in REVERSE order so the re-read of x starts
// with the tail that kernel 1 left resident in the 256 MB L3.
__global__ __launch_bounds__(256) void fused_conv_mul(const float* __restrict__ x,
                                                      const float2* __restrict__ ws2,
                                                      const float* __restrict__ w,
                                                      float* __restrict__ out) {
    __shared__ float sw[98];
    __shared__ float satt[64];
    const int t = threadIdx.x;
    if (t < 98) sw[t] = w[t];
    __syncthreads();

    const int blk  = (int)gridDim.x - 1 - (int)blockIdx.x;  // reversed traversal
    const int base = blk * 64;

    // Issue all x loads for this block up front (independent of the conv).
    const f32x4* x4 = (const f32x4*)(x + (size_t)base * C_);
    f32x4* o4       = (f32x4*)(out + (size_t)base * C_);
    f32x4 v0  = x4[ 0*256 + t];
    f32x4 v1  = x4[ 1*256 + t];
    f32x4 v2  = x4[ 2*256 + t];
    f32x4 v3  = x4[ 3*256 + t];
    f32x4 v4  = x4[ 4*256 + t];
    f32x4 v5  = x4[ 5*256 + t];
    f32x4 v6  = x4[ 6*256 + t];
    f32x4 v7  = x4[ 7*256 + t];
    f32x4 v8  = x4[ 8*256 + t];
    f32x4 v9  = x4[ 9*256 + t];
    f32x4 v10 = x4[10*256 + t];
    f32x4 v11 = x4[11*256 + t];

    if (t < 64) {
        const int p  = base + t;
        const int b  = p / (H_ * W_);
        const int r  = p - b * (H_ * W_);
        const int y  = r / W_;
        const int xx = r - y * W_;
        const float2* bimg = ws2 + (size_t)b * (H_ * W_);
        float acc = 0.0f;
        #pragma unroll
        for (int ky = 0; ky < 7; ++ky) {
            const int yy = y + ky - 3;
            if (yy < 0 || yy >= H_) continue;
            const float2* row = bimg + yy * W_;
            #pragma unroll
            for (int kx = 0; kx < 7; ++kx) {
                const int xc = xx + kx - 3;
                if (xc < 0 || xc >= W_) continue;
                float2 am = row[xc];
                acc = fmaf(am.x, sw[(ky * 7 + kx) * 2 + 0], acc);
                acc = fmaf(am.y, sw[(ky * 7 + kx) * 2 + 1], acc);
            }
        }
        satt[t] = 1.0f / (1.0f + __expf(-acc));
    }
    __syncthreads();

    // Multiply + nontemporal store (don't evict x from L3 mid-stream).
    #pragma unroll
    for (int j = 0; j < 12; ++j) {
        const int q = j * 256 + t;
        const float a = satt[q / C4];
        f32x4 v;
        switch (j) {
            case 0:  v = v0;  break; case 1:  v = v1;  break;
            case 2:  v = v2;  break; case 3:  v = v3;  break;
            case 4:  v = v4;  break; case 5:  v = v5;  break;
            case 6:  v = v6;  break; case 7:  v = v7;  break;
            case 8:  v = v8;  break; case 9:  v = v9;  break;
            case 10: v = v10; break; default: v = v11; break;
        }
        v *= a;
        __builtin_nontemporal_store(v, &o4[q]);
    }
}

extern "C" void kernel_launch(void* const* d_in, const int* in_sizes, int n_in,
                              void* d_out, int out_size, void* d_ws, size_t ws_size,
                              hipStream_t stream) {
    const float* x = (const float*)d_in[0];
    const float* w = (const float*)d_in[1];
    float* out = (float*)d_out;

    float2* ws2 = (float2*)d_ws;   // NPOS float2 = 3.2 MB

    // Kernel 1: 16 positions per block (4 waves x 4 positions/wave)
    reduce_kernel<<<NPOS / 16, 256, 0, stream>>>(x, ws2);

    // Kernel 2: 64 positions per block, conv+sigmoid+multiply fused
    fused_conv_mul<<<NPOS / 64, 256, 0, stream>>>(x, ws2, w, out);
}